// Round 1
// baseline (34696.051 us; speedup 1.0000x reference)
//
#include <hip/hip_runtime.h>

#define Hd 1024
#define Sd 4096
#define G4 4096   // 4*H

typedef __attribute__((ext_vector_type(8))) short    bf16x8;
typedef __attribute__((ext_vector_type(8))) unsigned short u16x8;
typedef __attribute__((ext_vector_type(4))) unsigned short u16x4;
typedef __attribute__((ext_vector_type(4))) float    f32x4;

// ---- ws layout (bytes) ----
#define WS_WHH_F 0u                 // 4096*1024*2 = 8388608
#define WS_WIH_F 8388608u           // 8388608
#define WS_EMB_F 16777216u          // 8388608
#define WS_XG    25165824u          // 4096*4096*2 = 33554432
#define WS_BIAS  58720256u          // 4096*4 = 16384
#define WS_HG    58736640u          // 2*1024*2 = 4096
#define WS_EPOCH 58740736u          // 4

__device__ __forceinline__ float b2f(unsigned short u) {
    return __uint_as_float(((unsigned)u) << 16);
}
__device__ __forceinline__ unsigned short f2b(float f) {
    unsigned u = __float_as_uint(f);
    unsigned r = u + 0x7fffu + ((u >> 16) & 1u);   // RNE
    return (unsigned short)(r >> 16);
}

// Pack a [R x 1024] f32 matrix (optionally row-gathered by idx) into MFMA
// A-fragment order: chunk(rb,kb) = 64 lanes x 8 bf16,
// elem(l,j) = src[rb*16 + (l&15)][kb*32 + (l>>4)*8 + j]
__global__ void pack_frag(const float* __restrict__ src, const int* __restrict__ idx,
                          unsigned short* __restrict__ dst) {
    const int rb = blockIdx.x;       // 0..255
    const int kb = blockIdx.y;       // 0..31
    const int l  = threadIdx.x;      // 0..63
    int row = rb * 16 + (l & 15);
    if (idx) row = idx[row];
    const float* s = src + (size_t)row * Hd + kb * 32 + ((l >> 4) & 3) * 8;
    float4 f0 = *(const float4*)s;
    float4 f1 = *(const float4*)(s + 4);
    u16x8 v;
    v[0]=f2b(f0.x); v[1]=f2b(f0.y); v[2]=f2b(f0.z); v[3]=f2b(f0.w);
    v[4]=f2b(f1.x); v[5]=f2b(f1.y); v[6]=f2b(f1.z); v[7]=f2b(f1.w);
    *(u16x8*)(dst + ((size_t)(rb * 32 + kb) * 64 + l) * 8) = v;
}

// bias = b_ih + b_hh; zero h_glob[0]; reset epoch
__global__ void init_k(const float* __restrict__ bih, const float* __restrict__ bhh,
                       float* __restrict__ bias, unsigned short* __restrict__ hg,
                       unsigned* __restrict__ epoch) {
    const int i = blockIdx.x * 256 + threadIdx.x;   // 0..4095
    bias[i] = bih[i] + bhh[i];
    if (i < Hd) hg[i] = 0;
    if (i == 0) *epoch = 0u;
}

// xg[s][n] = sum_k embs[s][k]*W_ih[n][k] + bias[n], bf16 out.
// Fragment-direct GEMM: no LDS; each wave does a 64x64 tile.
__global__ __launch_bounds__(256, 2)
void gemm_k(const unsigned short* __restrict__ Af, const unsigned short* __restrict__ Bf,
            const float* __restrict__ bias, unsigned short* __restrict__ xg) {
    const int w = threadIdx.x >> 6, l = threadIdx.x & 63;
    const int wid = blockIdx.x * 4 + w;      // 0..4095
    const int mg = wid >> 6;                 // 0..63
    const int ng = wid & 63;                 // 0..63

    f32x4 acc[4][4] = {};
    for (int kb = 0; kb < 32; ++kb) {
        bf16x8 a[4], b[4];
#pragma unroll
        for (int mi = 0; mi < 4; ++mi)
            a[mi] = *(const bf16x8*)(Af + (((size_t)(mg * 4 + mi) * 32 + kb) * 64 + l) * 8);
#pragma unroll
        for (int ni = 0; ni < 4; ++ni)
            b[ni] = *(const bf16x8*)(Bf + (((size_t)(ng * 4 + ni) * 32 + kb) * 64 + l) * 8);
#pragma unroll
        for (int mi = 0; mi < 4; ++mi)
#pragma unroll
            for (int ni = 0; ni < 4; ++ni)
                acc[mi][ni] = __builtin_amdgcn_mfma_f32_16x16x32_bf16(a[mi], b[ni], acc[mi][ni], 0, 0, 0);
    }
    // D layout: row = (l>>4)*4 + i, col = l&15 (per 16x16 block)
    const int r4 = (l >> 4) * 4, c = l & 15;
#pragma unroll
    for (int ni = 0; ni < 4; ++ni) {
        const int col = ng * 64 + ni * 16 + c;
        const float bv = bias[col];
#pragma unroll
        for (int mi = 0; mi < 4; ++mi) {
            const int rowb = mg * 64 + mi * 16 + r4;
#pragma unroll
            for (int i = 0; i < 4; ++i)
                xg[(size_t)(rowb + i) * G4 + col] = f2b(acc[mi][ni][i] + bv);
        }
    }
}

// Persistent LSTM scan. 64 WGs x 256 thr. WG j owns h-slice [j*16, j*16+16).
// Wave w computes gate w's 16 rows via 32 MFMAs with W_hh held in VGPRs.
__global__ __launch_bounds__(256, 1)
void scan_k(const unsigned short* __restrict__ Wf, const unsigned short* __restrict__ xg,
            unsigned short* __restrict__ hg, unsigned* __restrict__ epoch,
            float* __restrict__ out) {
    __shared__ float g_lds[64];   // [gate 0..3][r 0..15]
    __shared__ float c_s[16];

    const int j = blockIdx.x;                 // 0..63
    const int w = threadIdx.x >> 6, l = threadIdx.x & 63;
    const int rb = w * 64 + j;                // row-block: rows w*1024 + j*16 .. +16

    bf16x8 wfrag[32];
#pragma unroll
    for (int kb = 0; kb < 32; ++kb)
        wfrag[kb] = *(const bf16x8*)(Wf + (((size_t)rb * 32 + kb) * 64 + l) * 8);

    if (threadIdx.x < 16) c_s[threadIdx.x] = 0.f;
    __syncthreads();

    const int hoff = ((l >> 4) & 3) * 8;      // elems within each 32-chunk of h

    for (int t = 0; t < Sd; ++t) {
        const unsigned short* hsrc = hg + (t & 1) * Hd;
        f32x4 acc = {0.f, 0.f, 0.f, 0.f};
#pragma unroll
        for (int kb = 0; kb < 32; ++kb) {
            bf16x8 hf = *(const bf16x8*)(hsrc + kb * 32 + hoff);   // h replicated over all 16 B-cols
            acc = __builtin_amdgcn_mfma_f32_16x16x32_bf16(wfrag[kb], hf, acc, 0, 0, 0);
        }
        if ((l & 15) == 0) {   // lanes 0,16,32,48 hold rows (l>>4)*4 .. +4 (col 0)
            const int r0 = (l >> 4) * 4;
            u16x4 xv = *(const u16x4*)(xg + (size_t)t * G4 + w * Hd + j * 16 + r0);
#pragma unroll
            for (int i = 0; i < 4; ++i)
                g_lds[w * 16 + r0 + i] = acc[i] + b2f(xv[i]);
        }
        __syncthreads();
        if (threadIdx.x < 16) {   // wave 0: LSTM cell for this WG's 16 h-lanes
            const int r = threadIdx.x;
            float iv = g_lds[r],      fv = g_lds[16 + r];
            float gv = g_lds[32 + r], ov = g_lds[48 + r];
            iv = 1.f / (1.f + expf(-iv));
            fv = 1.f / (1.f + expf(-fv));
            gv = tanhf(gv);
            ov = 1.f / (1.f + expf(-ov));
            float c = fv * c_s[r] + iv * gv;
            c_s[r] = c;
            float h = ov * tanhf(c);
            out[(size_t)Hd + (size_t)t * Hd + j * 16 + r] = h;   // outs[t]
            if (t == Sd - 1) out[j * 16 + r] = h;                // final h
            hg[((t + 1) & 1) * Hd + j * 16 + r] = f2b(h);
        }
        if (threadIdx.x == 0) {
            __threadfence();   // publish h slice (agent scope)
            __hip_atomic_fetch_add(epoch, 1u, __ATOMIC_RELEASE, __HIP_MEMORY_SCOPE_AGENT);
            const unsigned target = 64u * (unsigned)(t + 1);
            while (__hip_atomic_load(epoch, __ATOMIC_RELAXED, __HIP_MEMORY_SCOPE_AGENT) < target)
                __builtin_amdgcn_s_sleep(2);
            __threadfence();   // acquire: invalidate stale L1/L2 before h reads
        }
        __syncthreads();
    }
}

extern "C" void kernel_launch(void* const* d_in, const int* in_sizes, int n_in,
                              void* d_out, int out_size, void* d_ws, size_t ws_size,
                              hipStream_t stream) {
    (void)in_sizes; (void)n_in; (void)out_size; (void)ws_size;
    const int*   x   = (const int*)  d_in[0];
    const float* emb = (const float*)d_in[1];
    const float* Wih = (const float*)d_in[2];
    const float* Whh = (const float*)d_in[3];
    const float* bih = (const float*)d_in[4];
    const float* bhh = (const float*)d_in[5];
    float* out = (float*)d_out;

    char* ws = (char*)d_ws;
    unsigned short* whh_f = (unsigned short*)(ws + WS_WHH_F);
    unsigned short* wih_f = (unsigned short*)(ws + WS_WIH_F);
    unsigned short* emb_f = (unsigned short*)(ws + WS_EMB_F);
    unsigned short* xgp   = (unsigned short*)(ws + WS_XG);
    float*          bias  = (float*)        (ws + WS_BIAS);
    unsigned short* hgl   = (unsigned short*)(ws + WS_HG);
    unsigned*       epoch = (unsigned*)      (ws + WS_EPOCH);

    init_k   <<<16, 256, 0, stream>>>(bih, bhh, bias, hgl, epoch);
    pack_frag<<<dim3(256, 32), 64, 0, stream>>>(Whh, nullptr, whh_f);
    pack_frag<<<dim3(256, 32), 64, 0, stream>>>(Wih, nullptr, wih_f);
    pack_frag<<<dim3(256, 32), 64, 0, stream>>>(emb, x,       emb_f);
    gemm_k   <<<1024, 256, 0, stream>>>(emb_f, wih_f, bias, xgp);
    scan_k   <<<64, 256, 0, stream>>>(whh_f, xgp, hgl, epoch, out);
}

// Round 2
// 18856.946 us; speedup vs baseline: 1.8400x; 1.8400x over previous
//
#include <hip/hip_runtime.h>

#define Hd 1024
#define Sd 4096
#define G4 4096   // 4*H

typedef __attribute__((ext_vector_type(8))) short    bf16x8;
typedef __attribute__((ext_vector_type(8))) unsigned short u16x8;
typedef __attribute__((ext_vector_type(4))) unsigned short u16x4;
typedef __attribute__((ext_vector_type(4))) float    f32x4;

// ---- ws layout (bytes) ----
#define WS_WHH_F 0u                 // 4096*1024*2 = 8388608
#define WS_WIH_F 8388608u           // 8388608
#define WS_EMB_F 16777216u          // 8388608
#define WS_XG    25165824u          // 4096*4096*2 = 33554432
#define WS_BIAS  58720256u          // 4096*4 = 16384
#define WS_HG    58736640u          // 2*1024*2 = 4096
#define WS_FLAGS 58740736u          // 64*4 = 256

__device__ __forceinline__ float b2f(unsigned short u) {
    return __uint_as_float(((unsigned)u) << 16);
}
__device__ __forceinline__ unsigned short f2b(float f) {
    unsigned u = __float_as_uint(f);
    unsigned r = u + 0x7fffu + ((u >> 16) & 1u);   // RNE
    return (unsigned short)(r >> 16);
}

// Pack a [R x 1024] f32 matrix (optionally row-gathered by idx) into MFMA
// A-fragment order: chunk(rb,kb) = 64 lanes x 8 bf16,
// elem(l,j) = src[rb*16 + (l&15)][kb*32 + (l>>4)*8 + j]
__global__ void pack_frag(const float* __restrict__ src, const int* __restrict__ idx,
                          unsigned short* __restrict__ dst) {
    const int rb = blockIdx.x;       // 0..255
    const int kb = blockIdx.y;       // 0..31
    const int l  = threadIdx.x;      // 0..63
    int row = rb * 16 + (l & 15);
    if (idx) row = idx[row];
    const float* s = src + (size_t)row * Hd + kb * 32 + ((l >> 4) & 3) * 8;
    float4 f0 = *(const float4*)s;
    float4 f1 = *(const float4*)(s + 4);
    u16x8 v;
    v[0]=f2b(f0.x); v[1]=f2b(f0.y); v[2]=f2b(f0.z); v[3]=f2b(f0.w);
    v[4]=f2b(f1.x); v[5]=f2b(f1.y); v[6]=f2b(f1.z); v[7]=f2b(f1.w);
    *(u16x8*)(dst + ((size_t)(rb * 32 + kb) * 64 + l) * 8) = v;
}

// bias = b_ih + b_hh; zero h_glob[0]; reset flags
__global__ void init_k(const float* __restrict__ bih, const float* __restrict__ bhh,
                       float* __restrict__ bias, unsigned short* __restrict__ hg,
                       unsigned* __restrict__ flags) {
    const int i = blockIdx.x * 256 + threadIdx.x;   // 0..4095
    bias[i] = bih[i] + bhh[i];
    if (i < Hd) hg[i] = 0;
    if (i < 64) flags[i] = 0u;
}

// xg[s][n] = sum_k embs[s][k]*W_ih[n][k] + bias[n], bf16 out.
// Fragment-direct GEMM: no LDS; each wave does a 64x64 tile.
__global__ __launch_bounds__(256, 2)
void gemm_k(const unsigned short* __restrict__ Af, const unsigned short* __restrict__ Bf,
            const float* __restrict__ bias, unsigned short* __restrict__ xg) {
    const int w = threadIdx.x >> 6, l = threadIdx.x & 63;
    const int wid = blockIdx.x * 4 + w;      // 0..4095
    const int mg = wid >> 6;                 // 0..63
    const int ng = wid & 63;                 // 0..63

    f32x4 acc[4][4] = {};
    for (int kb = 0; kb < 32; ++kb) {
        bf16x8 a[4], b[4];
#pragma unroll
        for (int mi = 0; mi < 4; ++mi)
            a[mi] = *(const bf16x8*)(Af + (((size_t)(mg * 4 + mi) * 32 + kb) * 64 + l) * 8);
#pragma unroll
        for (int ni = 0; ni < 4; ++ni)
            b[ni] = *(const bf16x8*)(Bf + (((size_t)(ng * 4 + ni) * 32 + kb) * 64 + l) * 8);
#pragma unroll
        for (int mi = 0; mi < 4; ++mi)
#pragma unroll
            for (int ni = 0; ni < 4; ++ni)
                acc[mi][ni] = __builtin_amdgcn_mfma_f32_16x16x32_bf16(a[mi], b[ni], acc[mi][ni], 0, 0, 0);
    }
    // D layout: row = (l>>4)*4 + i, col = l&15 (per 16x16 block)
    const int r4 = (l >> 4) * 4, c = l & 15;
#pragma unroll
    for (int ni = 0; ni < 4; ++ni) {
        const int col = ng * 64 + ni * 16 + c;
        const float bv = bias[col];
#pragma unroll
        for (int mi = 0; mi < 4; ++mi) {
            const int rowb = mg * 64 + mi * 16 + r4;
#pragma unroll
            for (int i = 0; i < 4; ++i)
                xg[(size_t)(rowb + i) * G4 + col] = f2b(acc[mi][ni][i] + bv);
        }
    }
}

// Persistent LSTM scan. 64 WGs x 256 thr. WG j owns h-slice [j*16, j*16+16).
// Wave w computes gate w's 16 rows via 32 MFMAs with W_hh held in VGPRs.
// Cross-WG exchange via LLC-resident (sc0 sc1) stores/loads: NO cache fences.
__global__ __launch_bounds__(256, 1)
void scan_k(const unsigned short* __restrict__ Wf, const unsigned short* __restrict__ xg,
            unsigned short* __restrict__ hg, unsigned* __restrict__ flags,
            float* __restrict__ out) {
    __shared__ float g_lds[64];   // [gate 0..3][r 0..15]
    __shared__ float c_s[16];

    const int j = blockIdx.x;                 // 0..63
    const int w = threadIdx.x >> 6, l = threadIdx.x & 63;
    const int rb = w * 64 + j;                // row-block: rows w*1024 + j*16 .. +16

    bf16x8 wfrag[32];
#pragma unroll
    for (int kb = 0; kb < 32; ++kb)
        wfrag[kb] = *(const bf16x8*)(Wf + (((size_t)rb * 32 + kb) * 64 + l) * 8);

    if (threadIdx.x < 16) c_s[threadIdx.x] = 0.f;
    __syncthreads();

    const int hoff = ((l >> 4) & 3) * 8;      // elems within each 32-chunk of h

    for (int t = 0; t < Sd; ++t) {
        // xg prefetch (normal cached load; read-once addresses, no staleness)
        u16x4 xv = {0, 0, 0, 0};
        const int r0 = (l >> 4) * 4;
        if ((l & 15) == 0)
            xv = *(const u16x4*)(xg + (size_t)t * G4 + w * Hd + j * 16 + r0);

        // h fragment loads: bypass L1+L2 (LLC is the coherence point)
        const unsigned short* hp = hg + (t & 1) * Hd + hoff;
        bf16x8 hbuf[32];
#pragma unroll
        for (int kb = 0; kb < 32; ++kb)
            asm volatile("global_load_dwordx4 %0, %1, off offset:%2 sc0 sc1"
                         : "=v"(hbuf[kb]) : "v"(hp), "i"(kb * 64));
        asm volatile("s_waitcnt vmcnt(0)" ::: "memory");
        __builtin_amdgcn_sched_barrier(0);

        f32x4 a0 = {0.f, 0.f, 0.f, 0.f}, a1 = {0.f, 0.f, 0.f, 0.f};
#pragma unroll
        for (int kb = 0; kb < 32; kb += 2) {
            a0 = __builtin_amdgcn_mfma_f32_16x16x32_bf16(wfrag[kb],     hbuf[kb],     a0, 0, 0, 0);
            a1 = __builtin_amdgcn_mfma_f32_16x16x32_bf16(wfrag[kb + 1], hbuf[kb + 1], a1, 0, 0, 0);
        }
        f32x4 acc = a0 + a1;

        if ((l & 15) == 0) {   // lanes 0,16,32,48 hold rows (l>>4)*4 .. +4 (col 0)
#pragma unroll
            for (int i = 0; i < 4; ++i)
                g_lds[w * 16 + r0 + i] = acc[i] + b2f(xv[i]);
        }
        __syncthreads();

        if (w == 0) {
            if (l < 16) {   // LSTM cell for this WG's 16 h-lanes
                const int r = l;
                float iv = g_lds[r],      fv = g_lds[16 + r];
                float gv = g_lds[32 + r], ov = g_lds[48 + r];
                iv = 1.f / (1.f + expf(-iv));
                fv = 1.f / (1.f + expf(-fv));
                gv = tanhf(gv);
                ov = 1.f / (1.f + expf(-ov));
                float c = fv * c_s[r] + iv * gv;
                c_s[r] = c;
                float h = ov * tanhf(c);
                out[(size_t)Hd + (size_t)t * Hd + j * 16 + r] = h;   // outs[t]
                if (t == Sd - 1) out[j * 16 + r] = h;                // final h

                // publish h (packed pairs) straight to LLC
                unsigned hv = (unsigned)f2b(h);
                unsigned ot = (unsigned)__shfl_xor((int)hv, 1, 64);
                if ((r & 1) == 0) {
                    unsigned packed = hv | (ot << 16);
                    unsigned* dst = (unsigned*)hg + ((t + 1) & 1) * (Hd / 2) + ((j * 16 + r) >> 1);
                    asm volatile("global_store_dword %0, %1, off sc0 sc1"
                                 :: "v"(dst), "v"(packed) : "memory");
                }
            }
            if (l == 0) {
                // wave-level wait: h stores (same wave) ack'd at LLC before flag
                asm volatile("s_waitcnt vmcnt(0)" ::: "memory");
                unsigned* fdst = flags + j;
                unsigned fval = (unsigned)(t + 1);
                asm volatile("global_store_dword %0, %1, off sc0 sc1"
                             :: "v"(fdst), "v"(fval) : "memory");
            }
            // wave-parallel barrier detect: lane l polls flag[l]
            const unsigned* fp = flags + l;
            unsigned e;
            while (true) {
                asm volatile("global_load_dword %0, %1, off sc0 sc1\n\ts_waitcnt vmcnt(0)"
                             : "=v"(e) : "v"(fp) : "memory");
                if (!__any(e < (unsigned)(t + 1))) break;
                __builtin_amdgcn_s_sleep(1);
            }
            __builtin_amdgcn_sched_barrier(0);
        }
        __syncthreads();
    }
}

extern "C" void kernel_launch(void* const* d_in, const int* in_sizes, int n_in,
                              void* d_out, int out_size, void* d_ws, size_t ws_size,
                              hipStream_t stream) {
    (void)in_sizes; (void)n_in; (void)out_size; (void)ws_size;
    const int*   x   = (const int*)  d_in[0];
    const float* emb = (const float*)d_in[1];
    const float* Wih = (const float*)d_in[2];
    const float* Whh = (const float*)d_in[3];
    const float* bih = (const float*)d_in[4];
    const float* bhh = (const float*)d_in[5];
    float* out = (float*)d_out;

    char* ws = (char*)d_ws;
    unsigned short* whh_f = (unsigned short*)(ws + WS_WHH_F);
    unsigned short* wih_f = (unsigned short*)(ws + WS_WIH_F);
    unsigned short* emb_f = (unsigned short*)(ws + WS_EMB_F);
    unsigned short* xgp   = (unsigned short*)(ws + WS_XG);
    float*          bias  = (float*)        (ws + WS_BIAS);
    unsigned short* hgl   = (unsigned short*)(ws + WS_HG);
    unsigned*       flags = (unsigned*)      (ws + WS_FLAGS);

    init_k   <<<16, 256, 0, stream>>>(bih, bhh, bias, hgl, flags);
    pack_frag<<<dim3(256, 32), 64, 0, stream>>>(Whh, nullptr, whh_f);
    pack_frag<<<dim3(256, 32), 64, 0, stream>>>(Wih, nullptr, wih_f);
    pack_frag<<<dim3(256, 32), 64, 0, stream>>>(emb, x,       emb_f);
    gemm_k   <<<1024, 256, 0, stream>>>(emb_f, wih_f, bias, xgp);
    scan_k   <<<64, 256, 0, stream>>>(whh_f, xgp, hgl, flags, out);
}

// Round 4
// 10861.452 us; speedup vs baseline: 3.1944x; 1.7361x over previous
//
#include <hip/hip_runtime.h>

#define Hd 1024
#define Sd 4096
#define G4 4096   // 4*H

typedef __attribute__((ext_vector_type(8))) short    bf16x8;
typedef __attribute__((ext_vector_type(8))) unsigned short u16x8;
typedef __attribute__((ext_vector_type(4))) unsigned short u16x4;
typedef __attribute__((ext_vector_type(4))) unsigned u32x4;
typedef __attribute__((ext_vector_type(4))) float    f32x4;

// ---- ws layout (bytes) ----
#define WS_WHH_F 0u                 // 4096*1024*2 = 8388608
#define WS_WIH_F 8388608u           // 8388608
#define WS_EMB_F 16777216u          // 8388608 (dead after gemm_k; hrec reuses its head)
#define WS_HREC  16777216u          // 2 buffers x 256 chunks x 16B = 8192
#define WS_XG    25165824u          // 4096*4096*2 = 33554432
#define WS_BIAS  58720256u          // 4096*4 = 16384

__device__ __forceinline__ float b2f(unsigned short u) {
    return __uint_as_float(((unsigned)u) << 16);
}
__device__ __forceinline__ unsigned short f2b(float f) {
    unsigned u = __float_as_uint(f);
    unsigned r = u + 0x7fffu + ((u >> 16) & 1u);   // RNE
    return (unsigned short)(r >> 16);
}
__device__ __forceinline__ float sigmoid_fast(float x) {
    return 1.f / (1.f + __expf(-x));   // inf-safe at both ends
}
__device__ __forceinline__ float tanh_fast(float x) {
    float e = __expf(2.f * fabsf(x));  // inf-safe: 2/(inf+1)=0 -> +-1
    return copysignf(1.f - 2.f / (e + 1.f), x);
}

// Pack a [R x 1024] f32 matrix (optionally row-gathered by idx) into MFMA
// A-fragment order: chunk(rb,kb) = 64 lanes x 8 bf16,
// elem(l,j) = src[rb*16 + (l&15)][kb*32 + (l>>4)*8 + j]
__global__ void pack_frag(const float* __restrict__ src, const int* __restrict__ idx,
                          unsigned short* __restrict__ dst) {
    const int rb = blockIdx.x;       // 0..255
    const int kb = blockIdx.y;       // 0..31
    const int l  = threadIdx.x;      // 0..63
    int row = rb * 16 + (l & 15);
    if (idx) row = idx[row];
    const float* s = src + (size_t)row * Hd + kb * 32 + ((l >> 4) & 3) * 8;
    float4 f0 = *(const float4*)s;
    float4 f1 = *(const float4*)(s + 4);
    u16x8 v;
    v[0]=f2b(f0.x); v[1]=f2b(f0.y); v[2]=f2b(f0.z); v[3]=f2b(f0.w);
    v[4]=f2b(f1.x); v[5]=f2b(f1.y); v[6]=f2b(f1.z); v[7]=f2b(f1.w);
    *(u16x8*)(dst + ((size_t)(rb * 32 + kb) * 64 + l) * 8) = v;
}

__global__ void init_k(const float* __restrict__ bih, const float* __restrict__ bhh,
                       float* __restrict__ bias) {
    const int i = blockIdx.x * 256 + threadIdx.x;   // 0..4095
    bias[i] = bih[i] + bhh[i];
}

// zero hrec buffer 0 (h_0 = 0, tags = 0). Runs AFTER gemm_k (hrec aliases emb_f head).
__global__ void zero_hrec_k(unsigned* __restrict__ hrec) {
    hrec[blockIdx.x * 256 + threadIdx.x] = 0u;      // 1024 dwords
}

// xg[s][n] = sum_k embs[s][k]*W_ih[n][k] + bias[n], bf16 out.
__global__ __launch_bounds__(256, 2)
void gemm_k(const unsigned short* __restrict__ Af, const unsigned short* __restrict__ Bf,
            const float* __restrict__ bias, unsigned short* __restrict__ xg) {
    const int w = threadIdx.x >> 6, l = threadIdx.x & 63;
    const int wid = blockIdx.x * 4 + w;      // 0..4095
    const int mg = wid >> 6;                 // 0..63
    const int ng = wid & 63;                 // 0..63

    f32x4 acc[4][4] = {};
    for (int kb = 0; kb < 32; ++kb) {
        bf16x8 a[4], b[4];
#pragma unroll
        for (int mi = 0; mi < 4; ++mi)
            a[mi] = *(const bf16x8*)(Af + (((size_t)(mg * 4 + mi) * 32 + kb) * 64 + l) * 8);
#pragma unroll
        for (int ni = 0; ni < 4; ++ni)
            b[ni] = *(const bf16x8*)(Bf + (((size_t)(ng * 4 + ni) * 32 + kb) * 64 + l) * 8);
#pragma unroll
        for (int mi = 0; mi < 4; ++mi)
#pragma unroll
            for (int ni = 0; ni < 4; ++ni)
                acc[mi][ni] = __builtin_amdgcn_mfma_f32_16x16x32_bf16(a[mi], b[ni], acc[mi][ni], 0, 0, 0);
    }
    const int r4 = (l >> 4) * 4, c = l & 15;
#pragma unroll
    for (int ni = 0; ni < 4; ++ni) {
        const int col = ng * 64 + ni * 16 + c;
        const float bv = bias[col];
#pragma unroll
        for (int mi = 0; mi < 4; ++mi) {
            const int rowb = mg * 64 + mi * 16 + r4;
#pragma unroll
            for (int i = 0; i < 4; ++i)
                xg[(size_t)(rowb + i) * G4 + col] = f2b(acc[mi][ni][i] + bv);
        }
    }
}

// Persistent LSTM scan. 32 WGs x 256 thr. WG r owns h[r*32, r*32+32).
// Wave w = gate w, 32 rows. Weights in VGPRs. h exchange = tagged 16B chunks
// at LLC scope (sc0 sc1): chunk i = {payload lo, tag, payload hi, tag},
// consumer thread i polls chunk i until both tags == t. No separate flags,
// no store-ack serialization.
__global__ __launch_bounds__(256, 1)
void scan_k(const unsigned short* __restrict__ Wf, const unsigned short* __restrict__ xg,
            unsigned* __restrict__ hrec, float* __restrict__ out) {
    __shared__ unsigned short h_s[1024];
    __shared__ float g_lds[128];   // [gate 0..3][lh 0..31]
    __shared__ float c_s[32];

    const int role = blockIdx.x;              // 0..31
    const int w = threadIdx.x >> 6, l = threadIdx.x & 63;
    const int rb0 = (w << 6) + role * 2;      // first of 2 row-blocks (gate w)

    bf16x8 wfrag[64];                          // 256 VGPRs of W_hh
#pragma unroll
    for (int kb = 0; kb < 32; ++kb) {
        wfrag[kb * 2]     = *(const bf16x8*)(Wf + (((size_t)rb0       * 32 + kb) * 64 + l) * 8);
        wfrag[kb * 2 + 1] = *(const bf16x8*)(Wf + (((size_t)(rb0 + 1) * 32 + kb) * 64 + l) * 8);
    }
    if (threadIdx.x < 32) c_s[threadIdx.x] = 0.f;
    __syncthreads();

    const int hoff = ((l >> 4) & 3) * 8;
    const int r0 = (l >> 4) << 2;
    unsigned* hsw = (unsigned*)h_s;

    for (int t = 0; t < Sd; ++t) {
        // xg prefetch: issued before the poll so HBM latency hides under it
        u16x4 xv0 = {0,0,0,0}, xv1 = {0,0,0,0};
        if ((l & 15) == 0) {
            const unsigned short* xp = xg + (size_t)t * G4 + (w << 10) + (role << 5) + r0;
            xv0 = *(const u16x4*)xp;
            xv1 = *(const u16x4*)(xp + 16);
        }

        // ---- poll own chunk of h_t (tagged data, LLC scope) ----
        const unsigned* myc = hrec + (t & 1) * 1024 + threadIdx.x * 4;
        const unsigned tt = (unsigned)t;
        u32x4 hv4;
        int guard = 0;
        while (true) {
            asm volatile("global_load_dwordx4 %0, %1, off sc0 sc1\n\ts_waitcnt vmcnt(0)"
                         : "=v"(hv4) : "v"(myc) : "memory");
            if (!__any((hv4[1] != tt) | (hv4[3] != tt))) break;
            if (++guard > 65536) break;   // safety: terminate instead of hanging
            __builtin_amdgcn_s_sleep(1);
        }
        __builtin_amdgcn_sched_barrier(0);
        hsw[threadIdx.x * 2]     = hv4[0];
        hsw[threadIdx.x * 2 + 1] = hv4[2];
        __syncthreads();

        // ---- 64 MFMAs: 4 interleaved 16-deep chains ----
        f32x4 a00 = {0,0,0,0}, a01 = {0,0,0,0}, a10 = {0,0,0,0}, a11 = {0,0,0,0};
#pragma unroll
        for (int kb = 0; kb < 32; kb += 2) {
            bf16x8 hf0 = *(const bf16x8*)(h_s + kb * 32 + hoff);
            bf16x8 hf1 = *(const bf16x8*)(h_s + (kb + 1) * 32 + hoff);
            a00 = __builtin_amdgcn_mfma_f32_16x16x32_bf16(wfrag[kb * 2],           hf0, a00, 0, 0, 0);
            a10 = __builtin_amdgcn_mfma_f32_16x16x32_bf16(wfrag[kb * 2 + 1],       hf0, a10, 0, 0, 0);
            a01 = __builtin_amdgcn_mfma_f32_16x16x32_bf16(wfrag[(kb + 1) * 2],     hf1, a01, 0, 0, 0);
            a11 = __builtin_amdgcn_mfma_f32_16x16x32_bf16(wfrag[(kb + 1) * 2 + 1], hf1, a11, 0, 0, 0);
        }
        f32x4 acc0 = a00 + a01, acc1 = a10 + a11;

        if ((l & 15) == 0) {   // lanes 0,16,32,48: rows r0..r0+3 of each row-block
#pragma unroll
            for (int i = 0; i < 4; ++i) {
                g_lds[(w << 5) + r0 + i]      = acc0[i] + b2f(xv0[i]);
                g_lds[(w << 5) + 16 + r0 + i] = acc1[i] + b2f(xv1[i]);
            }
        }
        __syncthreads();

        if (w == 0 && l < 32) {   // LSTM cell for this WG's 32 h-lanes
            float iv = sigmoid_fast(g_lds[l]);
            float fv = sigmoid_fast(g_lds[32 + l]);
            float gv = tanh_fast(g_lds[64 + l]);
            float ov = sigmoid_fast(g_lds[96 + l]);
            float c = fv * c_s[l] + iv * gv;
            c_s[l] = c;
            float h = ov * tanh_fast(c);
            out[(size_t)Hd + (size_t)t * Hd + (role << 5) + l] = h;
            if (t == Sd - 1) out[(role << 5) + l] = h;

            // pack 4 h values per 16B chunk: {lo, tag, hi, tag}; fire-and-forget
            unsigned hv = (unsigned)f2b(h);
            unsigned p  = hv | ((unsigned)__shfl_xor((int)hv, 1, 64) << 16); // even lanes: h(l),h(l+1)
            unsigned p2 = (unsigned)__shfl((int)p, (int)((l & ~3) + 2), 64); // h(l+2),h(l+3)
            if ((l & 3) == 0) {
                const unsigned tag = (unsigned)(t + 1);
                u32x4 val = {p, tag, p2, tag};
                unsigned* dst = hrec + ((t + 1) & 1) * 1024 + ((role << 3) + (l >> 2)) * 4;
                asm volatile("global_store_dwordx4 %0, %1, off sc0 sc1"
                             :: "v"(dst), "v"(val) : "memory");
            }
        }
        // stores from step t are guaranteed drained before the step-(t+2) WAW
        // reuse of the same addresses by the intervening poll's vmcnt(0).
        __syncthreads();
    }
}

extern "C" void kernel_launch(void* const* d_in, const int* in_sizes, int n_in,
                              void* d_out, int out_size, void* d_ws, size_t ws_size,
                              hipStream_t stream) {
    (void)in_sizes; (void)n_in; (void)out_size; (void)ws_size;
    const int*   x   = (const int*)  d_in[0];
    const float* emb = (const float*)d_in[1];
    const float* Wih = (const float*)d_in[2];
    const float* Whh = (const float*)d_in[3];
    const float* bih = (const float*)d_in[4];
    const float* bhh = (const float*)d_in[5];
    float* out = (float*)d_out;

    char* ws = (char*)d_ws;
    unsigned short* whh_f = (unsigned short*)(ws + WS_WHH_F);
    unsigned short* wih_f = (unsigned short*)(ws + WS_WIH_F);
    unsigned short* emb_f = (unsigned short*)(ws + WS_EMB_F);
    unsigned short* xgp   = (unsigned short*)(ws + WS_XG);
    float*          bias  = (float*)        (ws + WS_BIAS);
    unsigned*       hrec  = (unsigned*)      (ws + WS_HREC);

    init_k     <<<16, 256, 0, stream>>>(bih, bhh, bias);
    pack_frag  <<<dim3(256, 32), 64, 0, stream>>>(Whh, nullptr, whh_f);
    pack_frag  <<<dim3(256, 32), 64, 0, stream>>>(Wih, nullptr, wih_f);
    pack_frag  <<<dim3(256, 32), 64, 0, stream>>>(emb, x,       emb_f);
    gemm_k     <<<1024, 256, 0, stream>>>(emb_f, wih_f, bias, xgp);
    zero_hrec_k<<<4, 256, 0, stream>>>(hrec);          // after gemm: hrec aliases emb_f
    scan_k     <<<32, 256, 0, stream>>>(whh_f, xgp, hrec, out);
}